// Round 9
// baseline (22.299 us; speedup 1.0000x reference)
//
#include <hip/hip_runtime.h>

constexpr int NE = 8;       // N_ELEMENT
constexpr int NL = 32;      // N_LINES
constexpr int MB = 512;     // MINIBATCH
constexpr int SN = 1024;    // SAMPLE_N
constexpr float KS   = 0.01f / 1024.0f;  // SAMPLE_CM / SAMPLE_N
constexpr float I0   = 100000.0f;        // PROBE_I0
constexpr float OUTS = 0.05f;            // DET_SOLID_ANGLE_RATIO * SIGNAL_ATT

// Line-split: 1024 blocks = (row b) x (line-half h). Each block redundantly
// computes the row's prefix scan (xp re-read: +16 MB chip-wide) and streams
// only its 16 SA lines. 4 blocks/CU -> one block's SA stream hides another
// block's scan/reduce phases. No cross-block communication; each block owns
// 16 whole outputs. h==0 block writes the transmission scalar.
__global__ __launch_bounds__(256)
void ppm_kernel(const float* __restrict__ xp,   // [8][512][1024]
                const float* __restrict__ mu,   // [8]
                const float* __restrict__ fl,   // [32]
                const float* __restrict__ SA,   // [32][512*1024]
                float* __restrict__ out)        // [32*512 fl_signal | 512 trans]
{
    const int bh   = blockIdx.x;
    const int b    = bh >> 1;
    const int h    = bh & 1;                    // line-half: lines 16h..16h+15
    const int t    = threadIdx.x;
    const int lane = t & 63;
    const int wv   = t >> 6;

    __shared__ float s_wave[4];
    __shared__ float s_acc[256 * 17];   // [thread][line], stride 17: <=2-way
    __shared__ float s_part[256];       // [group(16)][line(16)]

    const size_t sarow = (size_t)b * SN;

    // ---- xp loads: 8 elements x 4 samples (float4, coalesced) ----
    float x[NE][4];
    #pragma unroll
    for (int e = 0; e < NE; ++e) {
        const float4 v = reinterpret_cast<const float4*>(
            xp + (size_t)e * (MB * SN) + sarow)[t];
        x[e][0] = v.x; x[e][1] = v.y; x[e][2] = v.z; x[e][3] = v.w;
    }

    // ---- attenuation increments + prefix scan (identical to R1) ----
    float a0 = 0.f, a1 = 0.f, a2 = 0.f, a3 = 0.f;
    #pragma unroll
    for (int e = 0; e < NE; ++e) {
        const float m = mu[e];
        a0 = fmaf(m, x[e][0], a0);
        a1 = fmaf(m, x[e][1], a1);
        a2 = fmaf(m, x[e][2], a2);
        a3 = fmaf(m, x[e][3], a3);
    }
    const float e1 = a0, e2 = a0 + a1, e3 = e2 + a2;
    const float T  = e3 + a3;

    float incl = T;
    #pragma unroll
    for (int d = 1; d < 64; d <<= 1) {
        const float v = __shfl_up(incl, d, 64);
        if (lane >= d) incl += v;
    }
    if (lane == 63) s_wave[wv] = incl;
    __syncthreads();

    float woff = 0.f;
    #pragma unroll
    for (int w2 = 0; w2 < 4; ++w2) woff += (w2 < wv) ? s_wave[w2] : 0.f;
    const float bex = woff + (incl - T);

    if (h == 0 && t == 0) {
        out[NL * MB + b] = KS * (s_wave[0] + s_wave[1] + s_wave[2] + s_wave[3]);
    }

    const float w0  = I0 * __expf(-KS * bex);
    const float w1  = I0 * __expf(-KS * (bex + e1));
    const float w2f = I0 * __expf(-KS * (bex + e2));
    const float w3  = I0 * __expf(-KS * (bex + e3));

    // fold weights into this block's 4 elements (e = 4h .. 4h+3)
    float y[4][4];
    #pragma unroll
    for (int i = 0; i < 4; ++i) {
        const int e = 4 * h + i;
        y[i][0] = w0  * x[e][0];
        y[i][1] = w1  * x[e][1];
        y[i][2] = w2f * x[e][2];
        y[i][3] = w3  * x[e][3];
    }

    // ---- stream this block's 16 SA lines (float4, coalesced) ----
    #pragma unroll
    for (int i = 0; i < 16; ++i) {
        const float4 sa = reinterpret_cast<const float4*>(
            SA + ((size_t)(16 * h + i) << 19) + sarow)[t];   // MB*SN = 2^19
        const int q = i >> 2;
        s_acc[t * 17 + i] = y[q][0] * sa.x + y[q][1] * sa.y
                          + y[q][2] * sa.z + y[q][3] * sa.w;
    }
    __syncthreads();

    // ---- 256 partials per line -> 16 group partials ----
    {
        const int l = t & 15, g = t >> 4;
        float s = 0.f;
        #pragma unroll
        for (int j = 0; j < 16; ++j) s += s_acc[(g * 16 + j) * 17 + l];
        s_part[t] = s;   // t == g*16 + l
    }
    __syncthreads();

    // ---- final: 16 group partials -> fl_signal[l][b] ----
    if (t < 16) {
        float tot = 0.f;
        #pragma unroll
        for (int g2 = 0; g2 < 16; ++g2) tot += s_part[g2 * 16 + t];
        const int l = 16 * h + t;
        out[l * MB + b] = OUTS * fl[l] * tot;
    }
}

extern "C" void kernel_launch(void* const* d_in, const int* in_sizes, int n_in,
                              void* d_out, int out_size, void* d_ws, size_t ws_size,
                              hipStream_t stream) {
    const float* xp = (const float*)d_in[0];
    const float* mu = (const float*)d_in[1];
    const float* fl = (const float*)d_in[2];
    const float* SA = (const float*)d_in[3];
    float* out = (float*)d_out;
    ppm_kernel<<<2 * MB, 256, 0, stream>>>(xp, mu, fl, SA, out);
}